// Round 3
// baseline (22650.089 us; speedup 1.0000x reference)
//
#include <hip/hip_runtime.h>
#include <hip/hip_bf16.h>
#include <math.h>

using bf16 = __hip_bfloat16;
typedef long long i64;

// ---------------- helpers ----------------
__device__ __forceinline__ float bf2f(unsigned short u) {
    union { unsigned int i; float f; } v; v.i = ((unsigned int)u) << 16; return v.f;
}
// mode-aware external-input load (idx in elements): mode0 = bf16, mode1 = f32
__device__ __forceinline__ float ldm(const void* p, size_t i, int mode) {
    return mode ? ((const float*)p)[i] : bf2f(((const unsigned short*)p)[i]);
}
__device__ __forceinline__ void stm(void* p, size_t i, int f32, float v) {
    if (f32) ((float*)p)[i] = v;
    else ((unsigned short*)p)[i] = __bfloat16_as_ushort(__float2bfloat16(v));
}
__device__ __forceinline__ float ldb(const bf16* p, size_t i) {
    return bf2f(((const unsigned short*)p)[i]);
}
__device__ __forceinline__ float gelu_exact(float x) {
    return 0.5f * x * (1.0f + erff(x * 0.70710678118654752f));
}

// ---------------- dtype probe ----------------
__global__ __launch_bounds__(256) void detect_kernel(
    const void* __restrict__ x, int n, int* __restrict__ modep)
{
    __shared__ float red[256];
    float m = 0.0f;
    for (int i = threadIdx.x; i < n; i += 256) {
        float v = fabsf(bf2f(((const unsigned short*)x)[i]));
        if (!isfinite(v)) v = 1e30f;
        m = fmaxf(m, v);
    }
    red[threadIdx.x] = m;
    __syncthreads();
    for (int s = 128; s; s >>= 1) {
        if (threadIdx.x < s) red[threadIdx.x] = fmaxf(red[threadIdx.x], red[threadIdx.x + s]);
        __syncthreads();
    }
    if (threadIdx.x == 0) *modep = (red[0] > 1e4f) ? 1 : 0;
}

// ---------------- ex MLP ----------------
__global__ __launch_bounds__(256) void ex1_kernel(
    const void* __restrict__ ex, const void* __restrict__ w1,
    const void* __restrict__ b1, float* __restrict__ h1, const int* __restrict__ modep)
{
    const int mode = *modep;
    __shared__ float exs[64];
    const int tid = threadIdx.x;
    const int b = blockIdx.y;
    const int n = blockIdx.x * 256 + tid;
    if (tid < 64) exs[tid] = ldm(ex, b * 64 + tid, mode);
    __syncthreads();
    float acc = ldm(b1, n, mode);
    for (int k = 0; k < 64; k++) acc += exs[k] * ldm(w1, (size_t)k * 2048 + n, mode);
    h1[(size_t)b * 2048 + n] = acc;
}

__global__ __launch_bounds__(256) void ex2_kernel(
    const float* __restrict__ h1, const void* __restrict__ w2,
    const void* __restrict__ b2, float* __restrict__ ex_enc, const int* __restrict__ modep)
{
    const int mode = *modep;
    __shared__ float hs[2048];
    const int tid = threadIdx.x;
    const int b = blockIdx.y;
    const int n = blockIdx.x * 256 + tid;
    for (int idx = tid; idx < 2048; idx += 256) hs[idx] = h1[(size_t)b * 2048 + idx];
    __syncthreads();
    float acc = ldm(b2, n, mode);
    for (int k = 0; k < 2048; k++) acc += hs[k] * ldm(w2, (size_t)k * 512 + n, mode);
    ex_enc[(size_t)b * 512 + n] = tanhf(acc);
}

// ---------------- conv1 ----------------
__global__ __launch_bounds__(256) void conv1_kernel(
    const void* __restrict__ x, const void* __restrict__ w,
    const void* __restrict__ b, bf16* __restrict__ out, const int* __restrict__ modep)
{
    const int mode = *modep;
    const int pix = blockIdx.x;
    const int bb = pix / 225, ij = pix % 225;
    const int i = ij / 15, j = ij % 15;
    const int tid = threadIdx.x;
    __shared__ float xs[18];
    if (tid < 18) {
        int c = tid & 1, dj = (tid >> 1) % 3, di = tid / 6;
        int ii = i + di - 1, jj = j + dj - 1;
        float v = 0.0f;
        if (ii >= 0 && ii < 15 && jj >= 0 && jj < 15)
            v = ldm(x, ((size_t)(bb * 15 + ii) * 15 + jj) * 2 + c, mode);
        xs[tid] = v;
    }
    __syncthreads();
    #pragma unroll
    for (int rep = 0; rep < 2; rep++) {
        int n = tid + rep * 256;
        float acc = ldm(b, n, mode);
        #pragma unroll
        for (int t = 0; t < 18; t++) acc += xs[t] * ldm(w, (size_t)t * 512 + n, mode);
        out[(size_t)pix * 512 + n] = __float2bfloat16(gelu_exact(acc));
    }
}

// ---------------- conv2 + epilogue ----------------
__global__ __launch_bounds__(256) void conv2_kernel(
    const bf16* __restrict__ in, const void* __restrict__ w,
    const void* __restrict__ bias, const float* __restrict__ ex_enc,
    bf16* __restrict__ hout, const int* __restrict__ modep)
{
    const int mode = *modep;
    __shared__ unsigned short xs[3 * 17 * 512];
    const int blk = blockIdx.x;
    const int bb = blk / 15, i = blk % 15;
    const int tid = threadIdx.x;
    for (int idx = tid; idx < 3 * 17 * 512; idx += 256) xs[idx] = 0;
    __syncthreads();
    for (int r = 0; r < 3; r++) {
        int row = i + r - 1;
        if (row < 0 || row >= 15) continue;
        const unsigned short* src = (const unsigned short*)(in + (size_t)(bb * 15 + row) * 15 * 512);
        for (int idx = tid; idx < 15 * 512; idx += 256) {
            int jj = idx >> 9, c = idx & 511;
            xs[(r * 17 + 1 + jj) * 512 + c] = src[idx];
        }
    }
    __syncthreads();

    const int n0 = tid, n1 = tid + 256;
    float acc0[15], acc1[15];
    {
        float b0 = ldm(bias, n0, mode), b1v = ldm(bias, n1, mode);
        #pragma unroll
        for (int p = 0; p < 15; p++) { acc0[p] = b0; acc1[p] = b1v; }
    }
    for (int di = 0; di < 3; di++)
    for (int dj = 0; dj < 3; dj++) {
        const size_t wbase = (size_t)(di * 3 + dj) * 512 * 512;
        const int xbase = (di * 17 + dj) * 512;
        for (int c = 0; c < 512; c++) {
            float w0 = ldm(w, wbase + (size_t)c * 512 + n0, mode);
            float w1 = ldm(w, wbase + (size_t)c * 512 + n1, mode);
            #pragma unroll
            for (int p = 0; p < 15; p++) {
                float xf = bf2f(xs[xbase + p * 512 + c]);
                acc0[p] += xf * w0;
                acc1[p] += xf * w1;
            }
        }
    }
    const float LG = 9.210340371976184f / 512.0f;
    const float SQ = 22.627416997969522f;
    float rate0 = expf(-(float)(2 * (n0 >> 1)) * LG);
    float rate1 = expf(-(float)(2 * (n1 >> 1)) * LG);
    float e0 = ex_enc[(size_t)bb * 512 + n0];
    float e1 = ex_enc[(size_t)bb * 512 + n1];
    float pr = (float)(i - 7);
    #pragma unroll
    for (int p = 0; p < 15; p++) {
        float pc = (float)(p - 7);
        float spe0 = ((n0 & 1) == 0) ? sinf(pr * rate0) : cosf(pc * rate0);
        float spe1 = ((n1 & 1) == 0) ? sinf(pr * rate1) : cosf(pc * rate1);
        size_t base = ((size_t)(bb * 15 + i) * 15 + p) * 512;
        hout[base + n0] = __float2bfloat16(gelu_exact(acc0[p]) * SQ + e0 + spe0);
        hout[base + n1] = __float2bfloat16(gelu_exact(acc1[p]) * SQ + e1 + spe1);
    }
}

// ---------------- generic GEMM with element offsets ----------------
// C[bm..][bn..] = act(A[a_eoff + row*lda + k] @ W[w_eoff + k*ldw + col] + bias[b_eoff + col])
// A: internal bf16 unless (a_ext && mode); W/bias external; C internal unless (c_ext && mode).
__global__ __launch_bounds__(256) void gemm_bias_act(
    const void* __restrict__ A, int lda, int a_ext, i64 a_eoff,
    const void* __restrict__ W, int ldw, i64 w_eoff,
    const void* __restrict__ bias, i64 b_eoff,
    void* __restrict__ C, int ldc, int c_ext, i64 c_eoff,
    int K, int act, const int* __restrict__ modep)
{
    const int mode = *modep;
    const int af = a_ext & mode;
    __shared__ float As[32][68];
    __shared__ float Bs[32][68];
    const int tid = threadIdx.x;
    const int bm = blockIdx.y * 64, bn = blockIdx.x * 64;
    const int tx = tid & 15, ty = tid >> 4;
    const int arow = tid >> 2, ak = (tid & 3) << 3;
    const int wk = tid >> 3, wn = (tid & 7) << 3;
    float acc[4][4] = {};

    for (int k0 = 0; k0 < K; k0 += 32) {
        const size_t aidx = (size_t)a_eoff + (size_t)(bm + arow) * lda + (k0 + ak);
        if (af) {
            const float* ap = (const float*)A + aidx;
            float4 a0 = *(const float4*)ap;
            float4 a1 = *(const float4*)(ap + 4);
            As[ak + 0][arow] = a0.x; As[ak + 1][arow] = a0.y;
            As[ak + 2][arow] = a0.z; As[ak + 3][arow] = a0.w;
            As[ak + 4][arow] = a1.x; As[ak + 5][arow] = a1.y;
            As[ak + 6][arow] = a1.z; As[ak + 7][arow] = a1.w;
        } else {
            const unsigned short* ap = (const unsigned short*)A + aidx;
            ushort4 a0 = *(const ushort4*)ap;
            ushort4 a1 = *(const ushort4*)(ap + 4);
            As[ak + 0][arow] = bf2f(a0.x); As[ak + 1][arow] = bf2f(a0.y);
            As[ak + 2][arow] = bf2f(a0.z); As[ak + 3][arow] = bf2f(a0.w);
            As[ak + 4][arow] = bf2f(a1.x); As[ak + 5][arow] = bf2f(a1.y);
            As[ak + 6][arow] = bf2f(a1.z); As[ak + 7][arow] = bf2f(a1.w);
        }
        const size_t widx = (size_t)w_eoff + (size_t)(k0 + wk) * ldw + (bn + wn);
        if (mode) {
            const float* wp = (const float*)W + widx;
            float4 w0 = *(const float4*)wp;
            float4 w1 = *(const float4*)(wp + 4);
            Bs[wk][wn + 0] = w0.x; Bs[wk][wn + 1] = w0.y;
            Bs[wk][wn + 2] = w0.z; Bs[wk][wn + 3] = w0.w;
            Bs[wk][wn + 4] = w1.x; Bs[wk][wn + 5] = w1.y;
            Bs[wk][wn + 6] = w1.z; Bs[wk][wn + 7] = w1.w;
        } else {
            const unsigned short* wp = (const unsigned short*)W + widx;
            ushort4 w0 = *(const ushort4*)wp;
            ushort4 w1 = *(const ushort4*)(wp + 4);
            Bs[wk][wn + 0] = bf2f(w0.x); Bs[wk][wn + 1] = bf2f(w0.y);
            Bs[wk][wn + 2] = bf2f(w0.z); Bs[wk][wn + 3] = bf2f(w0.w);
            Bs[wk][wn + 4] = bf2f(w1.x); Bs[wk][wn + 5] = bf2f(w1.y);
            Bs[wk][wn + 6] = bf2f(w1.z); Bs[wk][wn + 7] = bf2f(w1.w);
        }
        __syncthreads();
        #pragma unroll
        for (int k = 0; k < 32; k++) {
            float4 av = *(const float4*)&As[k][ty << 2];
            float4 bv = *(const float4*)&Bs[k][tx << 2];
            float a[4] = { av.x, av.y, av.z, av.w };
            float bb[4] = { bv.x, bv.y, bv.z, bv.w };
            #pragma unroll
            for (int ii = 0; ii < 4; ii++)
                #pragma unroll
                for (int jj = 0; jj < 4; jj++)
                    acc[ii][jj] += a[ii] * bb[jj];
        }
        __syncthreads();
    }
    const int cf = c_ext & mode;
    float bvals[4];
    #pragma unroll
    for (int jj = 0; jj < 4; jj++)
        bvals[jj] = ldm(bias, (size_t)b_eoff + bn + (tx << 2) + jj, mode);
    #pragma unroll
    for (int ii = 0; ii < 4; ii++) {
        size_t row = (size_t)(bm + (ty << 2) + ii);
        #pragma unroll
        for (int jj = 0; jj < 4; jj++) {
            float c = acc[ii][jj] + bvals[jj];
            if (act) c = gelu_exact(c);
            stm(C, (size_t)c_eoff + row * ldc + bn + (tx << 2) + jj, cf, c);
        }
    }
}

// ---------------- layernorm with residual ----------------
__global__ __launch_bounds__(256) void ln_res_kernel(
    const bf16* __restrict__ x, const bf16* __restrict__ res,
    const void* __restrict__ g, const void* __restrict__ b, i64 gb_eoff,
    void* __restrict__ dst, int dst_ext, const int* __restrict__ modep)
{
    const int mode = *modep;
    const size_t base = (size_t)blockIdx.x * 512;
    const int tid = threadIdx.x;
    float v0 = ldb(x, base + tid) + ldb(res, base + tid);
    float v1 = ldb(x, base + 256 + tid) + ldb(res, base + 256 + tid);
    __shared__ float ws[4], ws2[4];
    float s = v0 + v1;
    #pragma unroll
    for (int off = 32; off; off >>= 1) s += __shfl_xor(s, off);
    int wid = tid >> 6, lane = tid & 63;
    if (lane == 0) ws[wid] = s;
    __syncthreads();
    float mean = (ws[0] + ws[1] + ws[2] + ws[3]) * (1.0f / 512.0f);
    float d0 = v0 - mean, d1 = v1 - mean;
    float q = d0 * d0 + d1 * d1;
    #pragma unroll
    for (int off = 32; off; off >>= 1) q += __shfl_xor(q, off);
    if (lane == 0) ws2[wid] = q;
    __syncthreads();
    float var = (ws2[0] + ws2[1] + ws2[2] + ws2[3]) * (1.0f / 512.0f);
    float rs = rsqrtf(var + 1e-6f);
    const int df = dst_ext & mode;
    const size_t go = (size_t)gb_eoff;
    stm(dst, base + tid,       df, d0 * rs * ldm(g, go + tid, mode)       + ldm(b, go + tid, mode));
    stm(dst, base + 256 + tid, df, d1 * rs * ldm(g, go + 256 + tid, mode) + ldm(b, go + 256 + tid, mode));
}

// ---------------- cross attention ----------------
__global__ __launch_bounds__(256) void cross_attn_kernel(
    const bf16* __restrict__ q2, const bf16* __restrict__ kv,
    const void* __restrict__ mask, bf16* __restrict__ ao,
    int tok_base, int ntok, const int* __restrict__ modep)
{
    const int mode = *modep;
    const int gwid = (blockIdx.x * 256 + threadIdx.x) >> 6;
    const int lane = threadIdx.x & 63;
    if (gwid >= ntok * 8) return;
    const int t_local = gwid >> 3, head = gwid & 7;
    const int t = tok_base + t_local;
    float q = ldb(q2, (size_t)t * 512 + head * 64 + lane);
    const size_t kvbase = (size_t)t_local * 12 * 1024 + head * 64 + lane;
    float l[12], vv[12];
    #pragma unroll
    for (int s = 0; s < 12; s++) {
        float kd = ldb(kv, kvbase + (size_t)s * 1024);
        vv[s] = ldb(kv, kvbase + (size_t)s * 1024 + 512);
        float p = q * kd;
        #pragma unroll
        for (int off = 32; off; off >>= 1) p += __shfl_xor(p, off);
        l[s] = p * 0.125f + ldm(mask, s, mode) * (-1e9f);
    }
    float mx = l[0];
    #pragma unroll
    for (int s = 1; s < 12; s++) mx = fmaxf(mx, l[s]);
    float sum = 0.0f;
    #pragma unroll
    for (int s = 0; s < 12; s++) { l[s] = expf(l[s] - mx); sum += l[s]; }
    float o = 0.0f;
    #pragma unroll
    for (int s = 0; s < 12; s++) o += l[s] * vv[s];
    o /= sum;
    ao[(size_t)t * 512 + head * 64 + lane] = __float2bfloat16(o);
}

// ---------------- launch ----------------
extern "C" void kernel_launch(void* const* d_in, const int* in_sizes, int n_in,
                              void* d_out, int out_size, void* d_ws, size_t ws_size,
                              hipStream_t stream)
{
    const void* x        = d_in[0];
    const void* ex       = d_in[1];
    const void* enc      = d_in[2];
    const void* pad_mask = d_in[4];
    const void* ex_w1    = d_in[5];
    const void* ex_b1    = d_in[6];
    const void* ex_w2    = d_in[7];
    const void* ex_b2    = d_in[8];
    const void* conv_w1  = d_in[9];
    const void* conv_b1  = d_in[10];
    const void* conv_w2  = d_in[11];
    const void* conv_b2  = d_in[12];
    const void* wx_w     = d_in[13];
    const void* wx_b     = d_in[14];
    const void* wo1_w    = d_in[15];
    const void* wo1_b    = d_in[16];
    const void* wq_w     = d_in[17];
    const void* wq_b     = d_in[18];
    const void* wkv_w    = d_in[19];
    const void* wkv_b    = d_in[20];
    const void* wo2_w    = d_in[21];
    const void* wo2_b    = d_in[22];
    const void* ffn_w1   = d_in[23];
    const void* ffn_b1   = d_in[24];
    const void* ffn_w2   = d_in[25];
    const void* ffn_b2   = d_in[26];
    const void* ln_g     = d_in[27];
    const void* ln_b     = d_in[28];
    (void)ws_size; (void)in_sizes; (void)n_in; (void)out_size;

    char* wsb = (char*)d_ws;
    size_t off = 0;
    auto alloc = [&](size_t bytes) -> void* {
        void* p = wsb + off; off += (bytes + 255) & ~(size_t)255; return p;
    };
    int*   modep  = (int*)  alloc(256);
    float* ex_h1  = (float*)alloc((size_t)64 * 2048 * 4);
    float* ex_enc = (float*)alloc((size_t)64 * 512 * 4);
    bf16*  buf_h  = (bf16*) alloc((size_t)14400 * 512 * 2);
    bf16*  buf_a  = (bf16*) alloc((size_t)14400 * 512 * 2);
    bf16*  buf_b  = (bf16*) alloc((size_t)14400 * 512 * 2);
    bf16*  buf_t  = (bf16*) alloc((size_t)4800 * 2048 * 2);   // conv1 / kv-chunk / ffn-chunk

    detect_kernel<<<1, 256, 0, stream>>>(x, 28800, modep);
    ex1_kernel<<<dim3(8, 64), 256, 0, stream>>>(ex, ex_w1, ex_b1, ex_h1, modep);
    ex2_kernel<<<dim3(2, 64), 256, 0, stream>>>(ex_h1, ex_w2, ex_b2, ex_enc, modep);
    conv1_kernel<<<14400, 256, 0, stream>>>(x, conv_w1, conv_b1, buf_t, modep);
    conv2_kernel<<<960, 256, 0, stream>>>(buf_t, conv_w2, conv_b2, ex_enc, buf_h, modep);

    for (int L = 0; L < 4; L++) {
        // v = h @ wx[:,1024:1536] + b  (self-attn over T=1 => attn = v)
        gemm_bias_act<<<dim3(8, 225), 256, 0, stream>>>(
            buf_h, 512, 0, 0,
            wx_w, 1536, (i64)L * 512 * 1536 + 1024,
            wx_b, (i64)L * 1536 + 1024,
            buf_a, 512, 0, 0, 512, 0, modep);
        // attn1 = v @ wo1 + b
        gemm_bias_act<<<dim3(8, 225), 256, 0, stream>>>(
            buf_a, 512, 0, 0,
            wo1_w, 512, (i64)L * 512 * 512,
            wo1_b, (i64)L * 512,
            buf_b, 512, 0, 0, 512, 0, modep);
        ln_res_kernel<<<14400, 256, 0, stream>>>(
            buf_b, buf_h, ln_g, ln_b, (i64)(L * 3 + 0) * 512, buf_h, 0, modep);
        // q2 = out1 @ wq + b
        gemm_bias_act<<<dim3(8, 225), 256, 0, stream>>>(
            buf_h, 512, 0, 0,
            wq_w, 512, (i64)L * 512 * 512,
            wq_b, (i64)L * 512,
            buf_a, 512, 0, 0, 512, 0, modep);
        // cross attention: 20 chunks of 720 tokens (8640 enc rows each)
        for (int c = 0; c < 20; c++) {
            gemm_bias_act<<<dim3(16, 135), 256, 0, stream>>>(
                enc, 512, 1, (i64)c * 8640 * 512,
                wkv_w, 1024, (i64)L * 512 * 1024,
                wkv_b, (i64)L * 1024,
                buf_t, 1024, 0, 0, 512, 0, modep);
            cross_attn_kernel<<<1440, 256, 0, stream>>>(
                buf_a, buf_t, pad_mask, buf_b, c * 720, 720, modep);
        }
        // attn2 = ao @ wo2 + b
        gemm_bias_act<<<dim3(8, 225), 256, 0, stream>>>(
            buf_b, 512, 0, 0,
            wo2_w, 512, (i64)L * 512 * 512,
            wo2_b, (i64)L * 512,
            buf_a, 512, 0, 0, 512, 0, modep);
        ln_res_kernel<<<14400, 256, 0, stream>>>(
            buf_a, buf_h, ln_g, ln_b, (i64)(L * 3 + 1) * 512, buf_h, 0, modep);
        // FFN: 3 chunks of 4800 rows
        for (int c = 0; c < 3; c++) {
            gemm_bias_act<<<dim3(32, 75), 256, 0, stream>>>(
                buf_h, 512, 0, (i64)c * 4800 * 512,
                ffn_w1, 2048, (i64)L * 512 * 2048,
                ffn_b1, (i64)L * 2048,
                buf_t, 2048, 0, 0, 512, 1, modep);
            gemm_bias_act<<<dim3(8, 75), 256, 0, stream>>>(
                buf_t, 2048, 0, 0,
                ffn_w2, 512, (i64)L * 2048 * 512,
                ffn_b2, (i64)L * 512,
                buf_a, 512, 0, (i64)c * 4800 * 512, 2048, 0, modep);
        }
        void* dst = (L == 3) ? d_out : (void*)buf_h;
        ln_res_kernel<<<14400, 256, 0, stream>>>(
            buf_a, buf_h, ln_g, ln_b, (i64)(L * 3 + 2) * 512, dst, (L == 3) ? 1 : 0, modep);
    }
}